// Round 9
// baseline (929.918 us; speedup 1.0000x reference)
//
#include <hip/hip_runtime.h>
#include <hip/hip_fp16.h>
#include <math.h>

#define D 64
#define RB 1024          // nodes per range (must match >>10 / &1023 below)
#define EB 2048          // edges per partition block
#define NRMAX 128        // static LDS sizing; NR = ceil(N/RB) must be <= NRMAX
#define KHOPS 10
#define SLICES 4         // dim slices: 16 dims = 32B per node per slice

// ---- helpers ------------------------------------------------------------

typedef unsigned int u32x4 __attribute__((ext_vector_type(4)));
typedef union { u32x4 v; uint4 u; __half2 h[4]; int i[4]; } U4H;
typedef union { __half2 h; int i; } H2I;

__device__ __forceinline__ void nt_store16(uint4* p, u32x4 v) {
    __builtin_nontemporal_store(v, (u32x4*)p);
}
__device__ __forceinline__ int nt_load_i32(const int* p) {
    return __builtin_nontemporal_load(p);
}
__device__ __forceinline__ __half2 shfl_xor_h2(__half2 a, int m) {
    H2I u; u.h = a; u.i = __shfl_xor(u.i, m, 64); return u.h;
}

// ---- multisplit CSR build (no global atomics anywhere) ------------------

__global__ void countA(const int* __restrict__ dst, int* __restrict__ countsA_T,
                       int E, int NR, int NBLK) {
    __shared__ int hist[NRMAX];
    int t = threadIdx.x;
    for (int i = t; i < NR; i += 256) hist[i] = 0;
    __syncthreads();
    int base = blockIdx.x * EB + t;
    #pragma unroll
    for (int j = 0; j < EB / 256; ++j) {
        int e = base + j * 256;
        if (e < E) atomicAdd(&hist[dst[e] >> 10], 1);
    }
    __syncthreads();
    for (int i = t; i < NR; i += 256) countsA_T[i * NBLK + blockIdx.x] = hist[i];
}

__global__ void block_sums(const int* __restrict__ arr, int* __restrict__ bsum, int n) {
    int base = blockIdx.x * 1024;
    int t = threadIdx.x;
    int v = 0;
    #pragma unroll
    for (int j = 0; j < 4; ++j) {
        int i = base + t + j * 256;
        if (i < n) v += arr[i];
    }
    #pragma unroll
    for (int m = 32; m >= 1; m >>= 1) v += __shfl_xor(v, m, 64);
    __shared__ int ws[4];
    if ((t & 63) == 0) ws[t >> 6] = v;
    __syncthreads();
    if (t == 0) bsum[blockIdx.x] = ws[0] + ws[1] + ws[2] + ws[3];
}

__global__ void scan_bsums(int* __restrict__ bsum, int nb) {
    __shared__ int tmp[1024];
    int t = threadIdx.x;
    int v = (t < nb) ? bsum[t] : 0;
    tmp[t] = v;
    __syncthreads();
    for (int off = 1; off < 1024; off <<= 1) {
        int x = (t >= off) ? tmp[t - off] : 0;
        __syncthreads();
        tmp[t] += x;
        __syncthreads();
    }
    if (t < nb) bsum[t] = tmp[t] - v;
}

__global__ void gen_scan2(const int* __restrict__ arr, const int* __restrict__ bsum,
                          int* __restrict__ out, int n) {
    __shared__ int tmp[1024];
    int base = blockIdx.x * 1024;
    int t = threadIdx.x;
    int i = base + t;
    int v = (i < n) ? arr[i] : 0;
    tmp[t] = v;
    __syncthreads();
    for (int off = 1; off < 1024; off <<= 1) {
        int x = (t >= off) ? tmp[t - off] : 0;
        __syncthreads();
        tmp[t] += x;
        __syncthreads();
    }
    if (i < n) out[i] = bsum[blockIdx.x] + tmp[t] - v;
}

__global__ void passA2(const int* __restrict__ src, const int* __restrict__ dst,
                       const int* __restrict__ baseA, unsigned int* __restrict__ ebuf2,
                       int E, int NR, int NBLK) {
    __shared__ int cur[NRMAX];
    int t = threadIdx.x;
    for (int i = t; i < NR; i += 256) cur[i] = baseA[i * NBLK + blockIdx.x];
    __syncthreads();
    int base = blockIdx.x * EB + t;
    #pragma unroll
    for (int j = 0; j < EB / 256; ++j) {
        int e = base + j * 256;
        if (e < E) {
            int v = dst[e];
            int pos = atomicAdd(&cur[v >> 10], 1);
            ebuf2[pos] = (unsigned int)src[e] | ((unsigned int)(v & (RB - 1)) << 17);
        }
    }
}

__global__ void range_build(const unsigned int* __restrict__ ebuf2,
                            const int* __restrict__ baseA,
                            int* __restrict__ offsets, float* __restrict__ norm,
                            int* __restrict__ csr, int N, int E, int NR, int NBLK) {
    __shared__ int cnt[RB];
    __shared__ int sc[RB];
    int rg = blockIdx.x;
    int t = threadIdx.x;
    int r0 = baseA[rg * NBLK];
    int r1 = (rg + 1 < NR) ? baseA[(rg + 1) * NBLK] : E;
    cnt[t] = 0;
    __syncthreads();
    for (int i = r0 + t; i < r1; i += RB)
        atomicAdd(&cnt[ebuf2[i] >> 17], 1);
    __syncthreads();
    int v = cnt[t];
    sc[t] = v;
    __syncthreads();
    for (int off = 1; off < RB; off <<= 1) {
        int x = (t >= off) ? sc[t - off] : 0;
        __syncthreads();
        sc[t] += x;
        __syncthreads();
    }
    int excl = sc[t] - v;
    int node = rg * RB + t;
    if (node < N) {
        offsets[node] = r0 + excl;
        norm[node] = rsqrtf((float)(v > 1 ? v : 1));
    }
    if (rg == NR - 1 && t == 0) offsets[N] = E;
    __syncthreads();
    cnt[t] = r0 + excl;
    __syncthreads();
    for (int i = r0 + t; i < r1; i += RB) {
        unsigned int u = ebuf2[i];
        int pos = atomicAdd(&cnt[u >> 17], 1);
        csr[pos] = (int)(u & 0x1FFFFu);
    }
}

// ============ DEFERRED PATH: dim-sliced, XCD-L2-resident SpMM ============
// SpMM is dim-separable: h_out[:,d] = A . h_in[:,d]. Partition 64 dims into
// 4 slices of 16 (32B/node/slice = 3.2MB/slice <= 4MB XCD L2). Persistent
// 2048-block grid; blockIdx%8 = XCD (dispatch heuristic): slice = xcd&3, so
// slice s runs only on XCDs {s, s+4} and its 3.2MB buffer becomes L2-
// resident there -> random gathers served by L2 (~4.3TB/s/XCD) instead of
// the ~2.4TB/s LLC path that pinned rounds 0-7 at 37-56us/hop. csr reads
// are nt (stream, read 4x/hop), gout stores are nt (keep L2 for gin). If
// the XCD mapping heuristic fails, L2 dedup makes perf ~R4, not worse.
// Layout: buffer t, slice s, node u, half hf(16B):
//   gbase[t*gstride + s*(N+1)*2 + u*2 + hf]   (uint4 units)

__global__ void hop0_slice(const float4* __restrict__ feat,
                           const float* __restrict__ norm,
                           uint4* __restrict__ g0, int n) {
    int t = blockIdx.x * blockDim.x + threadIdx.x;
    int node = t >> 3;
    int q = t & 7;                       // q = 2*slice + half; dims q*8..q*8+7
    if (node > n) return;
    size_t sl = (size_t)(n + 1) * 2;
    uint4* dst = g0 + (size_t)(q >> 1) * sl + (size_t)node * 2 + (q & 1);
    if (node == n) { *dst = make_uint4(0u, 0u, 0u, 0u); return; }  // pad row
    float4 f0 = feat[node * 16 + 2 * q];
    float4 f1 = feat[node * 16 + 2 * q + 1];
    float nv = norm[node];
    U4H P;
    P.h[0] = __floats2half2_rn(f0.x * nv, f0.y * nv);
    P.h[1] = __floats2half2_rn(f0.z * nv, f0.w * nv);
    P.h[2] = __floats2half2_rn(f1.x * nv, f1.y * nv);
    P.h[3] = __floats2half2_rn(f1.z * nv, f1.w * nv);
    *dst = P.u;
}

// wave = 2 nodes x 16 edge-slots x 2 halves. lane = sub*32 + e*2 + hf.
// Base covers deg<=32 (2 gather rounds); deg>32 -> rare f32 slow path.
__global__ __launch_bounds__(256, 8)
void spmm_slice(const uint4* __restrict__ gin, const int* __restrict__ offsets,
                const int* __restrict__ csr, const float* __restrict__ norm,
                uint4* __restrict__ gout, int n) {
    int lane = threadIdx.x & 63;
    int w = threadIdx.x >> 6;            // wave 0..3
    int b = (int)blockIdx.x;
    int xcd = b & 7;                     // dispatch heuristic: XCD id
    int slice = xcd & 3;
    int hi = xcd >> 2;                   // XCD s: even groups, s+4: odd groups
    int j0 = b >> 3;                     // 0..255
    int sub = lane >> 5;
    int r = lane & 31;
    int e = r >> 1;                      // edge slot 0..15
    int hf = r & 1;                      // 16B half of the 32B slice row

    size_t sl = (size_t)(n + 1) * 2;
    const uint4* gs = gin + (size_t)slice * sl;
    uint4* os = gout + (size_t)slice * sl;

    int G = (n + 8) >> 3;                // node groups of 8 (covers pad node n)

    for (int j = j0;; j += 256) {
        int group = j * 2 + hi;
        if (group >= G) break;
        int node = group * 8 + w * 2 + sub;
        bool live = (node < n);
        int beg = 0, end = 0;
        if (live) { beg = offsets[node]; end = offsets[node + 1]; }
        int deg = end - beg;
        int dcap = deg < 32 ? deg : 32;
        int iA = (live && e < dcap)      ? nt_load_i32(&csr[beg + e])      : n;
        int iB = (live && e + 16 < dcap) ? nt_load_i32(&csr[beg + e + 16]) : n;
        U4H A, B;
        A.u = gs[(size_t)iA * 2 + hf];
        B.u = gs[(size_t)iB * 2 + hf];
        __builtin_amdgcn_sched_barrier(0);   // keep both gathers batched

        float f[8];
        if (!__any(deg > 32)) {
            // fast path: f16 depth 4 (A+B, one tree level), then f32 tree
            __half2 a0 = __hadd2(A.h[0], B.h[0]);
            __half2 a1 = __hadd2(A.h[1], B.h[1]);
            __half2 a2 = __hadd2(A.h[2], B.h[2]);
            __half2 a3 = __hadd2(A.h[3], B.h[3]);
            a0 = __hadd2(a0, shfl_xor_h2(a0, 2));
            a1 = __hadd2(a1, shfl_xor_h2(a1, 2));
            a2 = __hadd2(a2, shfl_xor_h2(a2, 2));
            a3 = __hadd2(a3, shfl_xor_h2(a3, 2));
            float2 q0 = __half22float2(a0), q1 = __half22float2(a1);
            float2 q2 = __half22float2(a2), q3 = __half22float2(a3);
            f[0]=q0.x; f[1]=q0.y; f[2]=q1.x; f[3]=q1.y;
            f[4]=q2.x; f[5]=q2.y; f[6]=q3.x; f[7]=q3.y;
            #pragma unroll
            for (int m = 4; m <= 16; m <<= 1) {
                #pragma unroll
                for (int jj = 0; jj < 8; ++jj) f[jj] += __shfl_xor(f[jj], m, 64);
            }
        } else {
            // slow path (deg>32 in wave): all-f32 + tail loop
            float2 qa0 = __half22float2(A.h[0]), qa1 = __half22float2(A.h[1]);
            float2 qa2 = __half22float2(A.h[2]), qa3 = __half22float2(A.h[3]);
            float2 qb0 = __half22float2(B.h[0]), qb1 = __half22float2(B.h[1]);
            float2 qb2 = __half22float2(B.h[2]), qb3 = __half22float2(B.h[3]);
            f[0]=qa0.x+qb0.x; f[1]=qa0.y+qb0.y; f[2]=qa1.x+qb1.x; f[3]=qa1.y+qb1.y;
            f[4]=qa2.x+qb2.x; f[5]=qa2.y+qb2.y; f[6]=qa3.x+qb3.x; f[7]=qa3.y+qb3.y;
            for (int i = beg + 32 + e; i < end; i += 16) {
                int ix = nt_load_i32(&csr[i]);
                U4H P; P.u = gs[(size_t)ix * 2 + hf];
                float2 p0 = __half22float2(P.h[0]), p1 = __half22float2(P.h[1]);
                float2 p2 = __half22float2(P.h[2]), p3 = __half22float2(P.h[3]);
                f[0]+=p0.x; f[1]+=p0.y; f[2]+=p1.x; f[3]+=p1.y;
                f[4]+=p2.x; f[5]+=p2.y; f[6]+=p3.x; f[7]+=p3.y;
            }
            #pragma unroll
            for (int m = 2; m <= 16; m <<= 1) {
                #pragma unroll
                for (int jj = 0; jj < 8; ++jj) f[jj] += __shfl_xor(f[jj], m, 64);
            }
        }

        if ((lane & 30) == 0) {              // e==0 lanes: one writer per (sub,hf)
            if (node == n) {
                os[(size_t)n * 2 + hf] = make_uint4(0u, 0u, 0u, 0u);   // pad row
            } else if (live) {
                float nv = norm[node];
                float s2 = nv * nv;          // g = (acc*nv)*nv
                U4H P;
                P.h[0] = __floats2half2_rn(f[0] * s2, f[1] * s2);
                P.h[1] = __floats2half2_rn(f[2] * s2, f[3] * s2);
                P.h[2] = __floats2half2_rn(f[4] * s2, f[5] * s2);
                P.h[3] = __floats2half2_rn(f[6] * s2, f[7] * s2);
                nt_store16(&os[(size_t)node * 2 + hf], P.v);
            }
        }
    }
}

// out = sum_t sigmoid((g_t . s)/nv) * g_t / nv  over t=0..KHOPS (slice layout)
__global__ void pool_epilogue_slice(const uint4* __restrict__ gbase, size_t gstride,
                                    const float* __restrict__ norm,
                                    const float* __restrict__ s,
                                    float4* __restrict__ out, int N) {
    int t0 = blockIdx.x * blockDim.x + threadIdx.x;
    int node = t0 >> 3;
    int q = t0 & 7;                      // dims q*8..q*8+7 (slice q>>1, half q&1)
    if (node >= N) return;
    size_t sl = (size_t)(N + 1) * 2;
    float inv_nv = 1.0f / norm[node];
    const float4* s4 = (const float4*)s;
    float4 sa = s4[2 * q], sb = s4[2 * q + 1];
    float o[8] = {0.f, 0.f, 0.f, 0.f, 0.f, 0.f, 0.f, 0.f};
    for (int t = 0; t <= KHOPS; ++t) {
        U4H P; P.u = gbase[(size_t)t * gstride + (size_t)(q >> 1) * sl
                           + (size_t)node * 2 + (q & 1)];
        float2 a0 = __half22float2(P.h[0]), a1 = __half22float2(P.h[1]);
        float2 a2 = __half22float2(P.h[2]), a3 = __half22float2(P.h[3]);
        float gf[8] = {a0.x, a0.y, a1.x, a1.y, a2.x, a2.y, a3.x, a3.y};
        float dot = gf[0] * sa.x + gf[1] * sa.y + gf[2] * sa.z + gf[3] * sa.w
                  + gf[4] * sb.x + gf[5] * sb.y + gf[6] * sb.z + gf[7] * sb.w;
        #pragma unroll
        for (int m = 1; m <= 4; m <<= 1) dot += __shfl_xor(dot, m, 64);
        float sig = 1.0f / (1.0f + expf(-dot * inv_nv));
        float sc = sig * inv_nv;
        #pragma unroll
        for (int jj = 0; jj < 8; ++jj) o[jj] += sc * gf[jj];
    }
    out[node * 16 + 2 * q]     = make_float4(o[0], o[1], o[2], o[3]);
    out[node * 16 + 2 * q + 1] = make_float4(o[4], o[5], o[6], o[7]);
}

// ============ FALLBACK PATH (non-deferred): R4 row-major kernels =========

__global__ void hop0(const float4* __restrict__ feat, const float* __restrict__ s,
                     const float* __restrict__ norm, uint4* __restrict__ g0,
                     float4* __restrict__ out, int n, int do_pool) {
    int t = blockIdx.x * blockDim.x + threadIdx.x;
    int node = t >> 3;
    int l = t & 7;
    if (node > n) return;
    if (node == n) {
        g0[(size_t)n * 8 + l] = make_uint4(0u, 0u, 0u, 0u);
        return;
    }
    float4 f0 = feat[node * 16 + 2 * l];
    float4 f1 = feat[node * 16 + 2 * l + 1];
    float nv = norm[node];
    U4H P;
    P.h[0] = __floats2half2_rn(f0.x * nv, f0.y * nv);
    P.h[1] = __floats2half2_rn(f0.z * nv, f0.w * nv);
    P.h[2] = __floats2half2_rn(f1.x * nv, f1.y * nv);
    P.h[3] = __floats2half2_rn(f1.z * nv, f1.w * nv);
    g0[(size_t)node * 8 + l] = P.u;
    if (do_pool) {
        const float4* s4 = (const float4*)s;
        float4 a = s4[2 * l], b = s4[2 * l + 1];
        float dot = f0.x * a.x + f0.y * a.y + f0.z * a.z + f0.w * a.w
                  + f1.x * b.x + f1.y * b.y + f1.z * b.z + f1.w * b.w;
        #pragma unroll
        for (int m = 1; m <= 4; m <<= 1) dot += __shfl_xor(dot, m, 64);
        float sig = 1.0f / (1.0f + expf(-dot));
        out[node * 16 + 2 * l]     = make_float4(sig * f0.x, sig * f0.y, sig * f0.z, sig * f0.w);
        out[node * 16 + 2 * l + 1] = make_float4(sig * f1.x, sig * f1.y, sig * f1.z, sig * f1.w);
    }
}

__global__ __launch_bounds__(256, 8)
void spmm_hop(const uint4* __restrict__ gin, const int* __restrict__ offsets,
              const int* __restrict__ csr, const float* __restrict__ norm,
              const float* __restrict__ s, uint4* __restrict__ gout,
              float4* __restrict__ out, int n, int do_pool, int write_g) {
    int lane = threadIdx.x & 63;
    int node = __builtin_amdgcn_readfirstlane(blockIdx.x * 4 + (threadIdx.x >> 6));
    if (node > n) return;
    int g = lane >> 3;
    int l = lane & 7;
    if (node == n) {
        if (write_g && g == 0) gout[(size_t)n * 8 + l] = make_uint4(0u, 0u, 0u, 0u);
        return;
    }
    int beg = offsets[node], end = offsets[node + 1];
    int deg = end - beg;
    int dcap = deg < 32 ? deg : 32;
    int idx = (lane < dcap) ? csr[beg + lane] : n;

    int u0 = __shfl(idx, g,      64);
    int u1 = __shfl(idx, g + 8,  64);
    int u2 = __shfl(idx, g + 16, 64);
    int u3 = __shfl(idx, g + 24, 64);
    U4H A0, A1, A2, A3;
    A0.u = gin[(size_t)u0 * 8 + l];
    A1.u = gin[(size_t)u1 * 8 + l];
    A2.u = gin[(size_t)u2 * 8 + l];
    A3.u = gin[(size_t)u3 * 8 + l];
    __builtin_amdgcn_sched_barrier(0);

    __half2 ah0, ah1, ah2, ah3;
    ah0 = __hadd2(A0.h[0], A1.h[0]); ah1 = __hadd2(A0.h[1], A1.h[1]);
    ah2 = __hadd2(A0.h[2], A1.h[2]); ah3 = __hadd2(A0.h[3], A1.h[3]);
    ah0 = __hadd2(ah0, A2.h[0]);     ah1 = __hadd2(ah1, A2.h[1]);
    ah2 = __hadd2(ah2, A2.h[2]);     ah3 = __hadd2(ah3, A2.h[3]);
    ah0 = __hadd2(ah0, A3.h[0]);     ah1 = __hadd2(ah1, A3.h[1]);
    ah2 = __hadd2(ah2, A3.h[2]);     ah3 = __hadd2(ah3, A3.h[3]);

    float2 q0 = __half22float2(ah0), q1 = __half22float2(ah1);
    float2 q2 = __half22float2(ah2), q3 = __half22float2(ah3);
    float acc[8] = {q0.x, q0.y, q1.x, q1.y, q2.x, q2.y, q3.x, q3.y};

    for (int i = beg + 32 + g; i < end; i += 8) {
        U4H P; P.u = gin[(size_t)csr[i] * 8 + l];
        float2 a0 = __half22float2(P.h[0]), a1 = __half22float2(P.h[1]);
        float2 a2 = __half22float2(P.h[2]), a3 = __half22float2(P.h[3]);
        acc[0] += a0.x; acc[1] += a0.y; acc[2] += a1.x; acc[3] += a1.y;
        acc[4] += a2.x; acc[5] += a2.y; acc[6] += a3.x; acc[7] += a3.y;
    }

    #pragma unroll
    for (int m = 8; m <= 32; m <<= 1) {
        #pragma unroll
        for (int jj = 0; jj < 8; ++jj) acc[jj] += __shfl_xor(acc[jj], m, 64);
    }

    float nv = norm[node];
    float h[8];
    #pragma unroll
    for (int jj = 0; jj < 8; ++jj) h[jj] = acc[jj] * nv;

    float sig = 0.f;
    if (do_pool) {
        const float4* s4 = (const float4*)s;
        float4 a = s4[2 * l], b = s4[2 * l + 1];
        float dot = h[0] * a.x + h[1] * a.y + h[2] * a.z + h[3] * a.w
                  + h[4] * b.x + h[5] * b.y + h[6] * b.z + h[7] * b.w;
        #pragma unroll
        for (int m = 1; m <= 4; m <<= 1) dot += __shfl_xor(dot, m, 64);
        sig = 1.0f / (1.0f + expf(-dot));
    }

    if (g == 0) {
        if (write_g) {
            U4H P;
            P.h[0] = __floats2half2_rn(h[0] * nv, h[1] * nv);
            P.h[1] = __floats2half2_rn(h[2] * nv, h[3] * nv);
            P.h[2] = __floats2half2_rn(h[4] * nv, h[5] * nv);
            P.h[3] = __floats2half2_rn(h[6] * nv, h[7] * nv);
            gout[(size_t)node * 8 + l] = P.u;
        }
        if (do_pool) {
            float4 o0 = out[node * 16 + 2 * l];
            float4 o1 = out[node * 16 + 2 * l + 1];
            o0.x += sig * h[0]; o0.y += sig * h[1]; o0.z += sig * h[2]; o0.w += sig * h[3];
            o1.x += sig * h[4]; o1.y += sig * h[5]; o1.z += sig * h[6]; o1.w += sig * h[7];
            out[node * 16 + 2 * l]     = o0;
            out[node * 16 + 2 * l + 1] = o1;
        }
    }
}

// ---- launcher -----------------------------------------------------------

extern "C" void kernel_launch(void* const* d_in, const int* in_sizes, int n_in,
                              void* d_out, int out_size, void* d_ws, size_t ws_size,
                              hipStream_t stream) {
    const float* feat = (const float*)d_in[0];
    const float* s    = (const float*)d_in[1];
    const int*   src  = (const int*)d_in[2];
    const int*   dst  = (const int*)d_in[3];

    int N = in_sizes[0] / D;
    int E = in_sizes[2];
    int NR   = (N + RB - 1) / RB;
    int NBLK = (E + EB - 1) / EB;
    int M    = NR * NBLK;
    int nchA = (M + 1023) / 1024;

    // fixed workspace layout
    int*   offsets  = (int*)d_ws;                  // N+1
    int*   csr      = offsets + (N + 1);           // E
    float* norm     = (float*)(csr + E);           // N
    int*   countsA  = (int*)(norm + N);            // M
    int*   baseA    = countsA + M;                 // M
    int*   bsumA    = baseA + M;                   // nchA
    uintptr_t p = (uintptr_t)(bsumA + nchA);
    p = (p + 255) & ~(uintptr_t)255;
    uint4* gbase = (uint4*)p;                      // (N+1)*128B per buffer
    size_t gstride = (size_t)(N + 1) * 8;          // uint4 per buffer

    size_t fixed_bytes = (uintptr_t)gbase - (uintptr_t)d_ws;
    int deferred = (ws_size >= fixed_bytes + (size_t)(KHOPS + 1) * gstride * sizeof(uint4)) ? 1 : 0;

    // ebuf2 aliases g buffer #1 (consumed by range_build before any hop writes it)
    unsigned int* ebuf2 = (unsigned int*)(gbase + gstride);

    countA<<<NBLK, 256, 0, stream>>>(dst, countsA, E, NR, NBLK);
    block_sums<<<nchA, 256, 0, stream>>>(countsA, bsumA, M);
    scan_bsums<<<1, 1024, 0, stream>>>(bsumA, nchA);
    gen_scan2<<<nchA, 1024, 0, stream>>>(countsA, bsumA, baseA, M);
    passA2<<<NBLK, 256, 0, stream>>>(src, dst, baseA, ebuf2, E, NR, NBLK);
    range_build<<<NR, RB, 0, stream>>>(ebuf2, baseA, offsets, norm, csr, N, E, NR, NBLK);

    float4* outp = (float4*)d_out;
    int nb_node8 = ((N + 1) * 8 + 255) / 256;      // covers pad node N

    if (deferred) {
        hop0_slice<<<nb_node8, 256, 0, stream>>>((const float4*)feat, norm, gbase, N);
        for (int t = 0; t < KHOPS; ++t) {
            spmm_slice<<<2048, 256, 0, stream>>>(
                gbase + (size_t)t * gstride, offsets, csr, norm,
                gbase + (size_t)(t + 1) * gstride, N);
        }
        pool_epilogue_slice<<<nb_node8, 256, 0, stream>>>(gbase, gstride, norm, s, outp, N);
    } else {
        hop0<<<nb_node8, 256, 0, stream>>>((const float4*)feat, s, norm, gbase,
                                           outp, N, 1);
        int nb_spmm = (N + 4) / 4;
        uint4* gin = gbase;
        uint4* gout = gbase + gstride;
        for (int t = 0; t < KHOPS; ++t) {
            spmm_hop<<<nb_spmm, 256, 0, stream>>>(
                gin, offsets, csr, norm, s, gout, outp, N, 1, (t < KHOPS - 1) ? 1 : 0);
            uint4* tmp = gin; gin = gout; gout = tmp;
        }
    }
}

// Round 10
// 505.563 us; speedup vs baseline: 1.8394x; 1.8394x over previous
//
#include <hip/hip_runtime.h>
#include <hip/hip_fp16.h>
#include <math.h>

#define D 64
#define RB 1024          // nodes per range (must match >>10 / &1023 below)
#define EB 2048          // edges per partition block
#define NRMAX 128        // static LDS sizing; NR = ceil(N/RB) must be <= NRMAX
#define KHOPS 10

// ---- helpers ------------------------------------------------------------

typedef union { uint4 u; __half2 h[4]; } U4H;

// ---- multisplit CSR build (no global atomics anywhere) ------------------

__global__ void countA(const int* __restrict__ dst, int* __restrict__ countsA_T,
                       int E, int NR, int NBLK) {
    __shared__ int hist[NRMAX];
    int t = threadIdx.x;
    for (int i = t; i < NR; i += 256) hist[i] = 0;
    __syncthreads();
    int base = blockIdx.x * EB + t;
    #pragma unroll
    for (int j = 0; j < EB / 256; ++j) {
        int e = base + j * 256;
        if (e < E) atomicAdd(&hist[dst[e] >> 10], 1);
    }
    __syncthreads();
    for (int i = t; i < NR; i += 256) countsA_T[i * NBLK + blockIdx.x] = hist[i];
}

__global__ void block_sums(const int* __restrict__ arr, int* __restrict__ bsum, int n) {
    int base = blockIdx.x * 1024;
    int t = threadIdx.x;
    int v = 0;
    #pragma unroll
    for (int j = 0; j < 4; ++j) {
        int i = base + t + j * 256;
        if (i < n) v += arr[i];
    }
    #pragma unroll
    for (int m = 32; m >= 1; m >>= 1) v += __shfl_xor(v, m, 64);
    __shared__ int ws[4];
    if ((t & 63) == 0) ws[t >> 6] = v;
    __syncthreads();
    if (t == 0) bsum[blockIdx.x] = ws[0] + ws[1] + ws[2] + ws[3];
}

__global__ void scan_bsums(int* __restrict__ bsum, int nb) {
    __shared__ int tmp[1024];
    int t = threadIdx.x;
    int v = (t < nb) ? bsum[t] : 0;
    tmp[t] = v;
    __syncthreads();
    for (int off = 1; off < 1024; off <<= 1) {
        int x = (t >= off) ? tmp[t - off] : 0;
        __syncthreads();
        tmp[t] += x;
        __syncthreads();
    }
    if (t < nb) bsum[t] = tmp[t] - v;
}

__global__ void gen_scan2(const int* __restrict__ arr, const int* __restrict__ bsum,
                          int* __restrict__ out, int n) {
    __shared__ int tmp[1024];
    int base = blockIdx.x * 1024;
    int t = threadIdx.x;
    int i = base + t;
    int v = (i < n) ? arr[i] : 0;
    tmp[t] = v;
    __syncthreads();
    for (int off = 1; off < 1024; off <<= 1) {
        int x = (t >= off) ? tmp[t - off] : 0;
        __syncthreads();
        tmp[t] += x;
        __syncthreads();
    }
    if (i < n) out[i] = bsum[blockIdx.x] + tmp[t] - v;
}

__global__ void passA2(const int* __restrict__ src, const int* __restrict__ dst,
                       const int* __restrict__ baseA, unsigned int* __restrict__ ebuf2,
                       int E, int NR, int NBLK) {
    __shared__ int cur[NRMAX];
    int t = threadIdx.x;
    for (int i = t; i < NR; i += 256) cur[i] = baseA[i * NBLK + blockIdx.x];
    __syncthreads();
    int base = blockIdx.x * EB + t;
    #pragma unroll
    for (int j = 0; j < EB / 256; ++j) {
        int e = base + j * 256;
        if (e < E) {
            int v = dst[e];
            int pos = atomicAdd(&cur[v >> 10], 1);
            ebuf2[pos] = (unsigned int)src[e] | ((unsigned int)(v & (RB - 1)) << 17);
        }
    }
}

__global__ void range_build(const unsigned int* __restrict__ ebuf2,
                            const int* __restrict__ baseA,
                            int* __restrict__ offsets, float* __restrict__ norm,
                            int* __restrict__ csr, int N, int E, int NR, int NBLK) {
    __shared__ int cnt[RB];
    __shared__ int sc[RB];
    int rg = blockIdx.x;
    int t = threadIdx.x;
    int r0 = baseA[rg * NBLK];
    int r1 = (rg + 1 < NR) ? baseA[(rg + 1) * NBLK] : E;
    cnt[t] = 0;
    __syncthreads();
    for (int i = r0 + t; i < r1; i += RB)
        atomicAdd(&cnt[ebuf2[i] >> 17], 1);
    __syncthreads();
    int v = cnt[t];
    sc[t] = v;
    __syncthreads();
    for (int off = 1; off < RB; off <<= 1) {
        int x = (t >= off) ? sc[t - off] : 0;
        __syncthreads();
        sc[t] += x;
        __syncthreads();
    }
    int excl = sc[t] - v;
    int node = rg * RB + t;
    if (node < N) {
        offsets[node] = r0 + excl;
        norm[node] = rsqrtf((float)(v > 1 ? v : 1));
    }
    if (rg == NR - 1 && t == 0) offsets[N] = E;
    __syncthreads();
    cnt[t] = r0 + excl;
    __syncthreads();
    for (int i = r0 + t; i < r1; i += RB) {
        unsigned int u = ebuf2[i];
        int pos = atomicAdd(&cnt[u >> 17], 1);
        csr[pos] = (int)(u & 0x1FFFFu);
    }
}

// ---- hop 0: g0 = f16(f*norm); if do_pool also out = sigmoid(f.s)*f ------
// 8 lanes per node, 8 dims (2 float4) per lane. Row N of g0 is the shared
// all-zero pad row that lets spmm_hop gather without per-lane masking.
// GRID MUST COVER (N+1)*8 THREADS so the pad row actually gets zeroed.

__global__ void hop0(const float4* __restrict__ feat, const float* __restrict__ s,
                     const float* __restrict__ norm, uint4* __restrict__ g0,
                     float4* __restrict__ out, int n, int do_pool) {
    int t = blockIdx.x * blockDim.x + threadIdx.x;
    int node = t >> 3;
    int l = t & 7;
    if (node > n) return;
    if (node == n) {                           // zero pad row
        g0[(size_t)n * 8 + l] = make_uint4(0u, 0u, 0u, 0u);
        return;
    }
    float4 f0 = feat[node * 16 + 2 * l];
    float4 f1 = feat[node * 16 + 2 * l + 1];
    float nv = norm[node];
    U4H P;
    P.h[0] = __floats2half2_rn(f0.x * nv, f0.y * nv);
    P.h[1] = __floats2half2_rn(f0.z * nv, f0.w * nv);
    P.h[2] = __floats2half2_rn(f1.x * nv, f1.y * nv);
    P.h[3] = __floats2half2_rn(f1.z * nv, f1.w * nv);
    g0[(size_t)node * 8 + l] = P.u;
    if (do_pool) {
        const float4* s4 = (const float4*)s;
        float4 a = s4[2 * l], b = s4[2 * l + 1];
        float dot = f0.x * a.x + f0.y * a.y + f0.z * a.z + f0.w * a.w
                  + f1.x * b.x + f1.y * b.y + f1.z * b.z + f1.w * b.w;
        #pragma unroll
        for (int m = 1; m <= 4; m <<= 1) dot += __shfl_xor(dot, m, 64);
        float sig = 1.0f / (1.0f + expf(-dot));
        out[node * 16 + 2 * l]     = make_float4(sig * f0.x, sig * f0.y, sig * f0.z, sig * f0.w);
        out[node * 16 + 2 * l + 1] = make_float4(sig * f1.x, sig * f1.y, sig * f1.z, sig * f1.w);
    }
}

// ---- hop t: gather-SpMM (f16 rows, packed-f16 accumulate) ---------------
// wave per node; lane = 8*g + l. The 4 row-gathers are UNCONDITIONAL and
// straight-line, pinned ahead of all consumes by sched_barrier(0). This is
// the measured-best structure (R4: 508us total, ~37us/hop, 87G line-
// touches/s -- the empirical CU<->L2 random-transaction ceiling; per-edge
// demand is 2 fully-used 64B lines, the structural minimum). Invalid edge
// slots gather the all-zero pad row n: exact +0 in f16, bit-identical, and
// pad lines stay L1-hot so they cost no L2 transactions.

__global__ __launch_bounds__(256, 8)
void spmm_hop(const uint4* __restrict__ gin, const int* __restrict__ offsets,
              const int* __restrict__ csr, const float* __restrict__ norm,
              const float* __restrict__ s, uint4* __restrict__ gout,
              float4* __restrict__ out, int n, int do_pool, int write_g) {
    int lane = threadIdx.x & 63;
    int node = __builtin_amdgcn_readfirstlane(blockIdx.x * 4 + (threadIdx.x >> 6));
    if (node > n) return;            // wave-uniform exit
    int g = lane >> 3;
    int l = lane & 7;
    if (node == n) {                 // maintain zero pad row in gout
        if (write_g && g == 0) gout[(size_t)n * 8 + l] = make_uint4(0u, 0u, 0u, 0u);
        return;
    }
    int beg = offsets[node], end = offsets[node + 1];   // s_loads (node is SGPR)
    int deg = end - beg;
    int dcap = deg < 32 ? deg : 32;
    int idx = (lane < dcap) ? csr[beg + lane] : n;      // n = zero pad row

    // distribute indices, then issue all 4 gathers back-to-back
    int u0 = __shfl(idx, g,      64);
    int u1 = __shfl(idx, g + 8,  64);
    int u2 = __shfl(idx, g + 16, 64);
    int u3 = __shfl(idx, g + 24, 64);
    U4H A0, A1, A2, A3;
    A0.u = gin[(size_t)u0 * 8 + l];
    A1.u = gin[(size_t)u1 * 8 + l];
    A2.u = gin[(size_t)u2 * 8 + l];
    A3.u = gin[(size_t)u3 * 8 + l];
    __builtin_amdgcn_sched_barrier(0);   // loads stay above; consumes stay below

    __half2 ah0, ah1, ah2, ah3;
    ah0 = __hadd2(A0.h[0], A1.h[0]); ah1 = __hadd2(A0.h[1], A1.h[1]);
    ah2 = __hadd2(A0.h[2], A1.h[2]); ah3 = __hadd2(A0.h[3], A1.h[3]);
    ah0 = __hadd2(ah0, A2.h[0]);     ah1 = __hadd2(ah1, A2.h[1]);
    ah2 = __hadd2(ah2, A2.h[2]);     ah3 = __hadd2(ah3, A2.h[3]);
    ah0 = __hadd2(ah0, A3.h[0]);     ah1 = __hadd2(ah1, A3.h[1]);
    ah2 = __hadd2(ah2, A3.h[2]);     ah3 = __hadd2(ah3, A3.h[3]);

    float2 q0 = __half22float2(ah0), q1 = __half22float2(ah1);
    float2 q2 = __half22float2(ah2), q3 = __half22float2(ah3);
    float acc[8] = {q0.x, q0.y, q1.x, q1.y, q2.x, q2.y, q3.x, q3.y};

    for (int i = beg + 32 + g; i < end; i += 8) {   // deg>32: rare (P ~ 1e-4)
        U4H P; P.u = gin[(size_t)csr[i] * 8 + l];
        float2 a0 = __half22float2(P.h[0]), a1 = __half22float2(P.h[1]);
        float2 a2 = __half22float2(P.h[2]), a3 = __half22float2(P.h[3]);
        acc[0] += a0.x; acc[1] += a0.y; acc[2] += a1.x; acc[3] += a1.y;
        acc[4] += a2.x; acc[5] += a2.y; acc[6] += a3.x; acc[7] += a3.y;
    }

    // reduce across the 8 edge-subgroups (lane bits 3,4,5) in f32
    #pragma unroll
    for (int m = 8; m <= 32; m <<= 1) {
        #pragma unroll
        for (int jj = 0; jj < 8; ++jj) acc[jj] += __shfl_xor(acc[jj], m, 64);
    }

    float nv = norm[node];
    float h[8];
    #pragma unroll
    for (int jj = 0; jj < 8; ++jj) h[jj] = acc[jj] * nv;

    float sig = 0.f;
    if (do_pool) {                   // wave-uniform flag
        const float4* s4 = (const float4*)s;
        float4 a = s4[2 * l], b = s4[2 * l + 1];
        float dot = h[0] * a.x + h[1] * a.y + h[2] * a.z + h[3] * a.w
                  + h[4] * b.x + h[5] * b.y + h[6] * b.z + h[7] * b.w;
        #pragma unroll
        for (int m = 1; m <= 4; m <<= 1) dot += __shfl_xor(dot, m, 64);
        sig = 1.0f / (1.0f + expf(-dot));
    }

    if (g == 0) {
        if (write_g) {
            U4H P;
            P.h[0] = __floats2half2_rn(h[0] * nv, h[1] * nv);
            P.h[1] = __floats2half2_rn(h[2] * nv, h[3] * nv);
            P.h[2] = __floats2half2_rn(h[4] * nv, h[5] * nv);
            P.h[3] = __floats2half2_rn(h[6] * nv, h[7] * nv);
            gout[(size_t)node * 8 + l] = P.u;
        }
        if (do_pool) {
            float4 o0 = out[node * 16 + 2 * l];
            float4 o1 = out[node * 16 + 2 * l + 1];
            o0.x += sig * h[0]; o0.y += sig * h[1]; o0.z += sig * h[2]; o0.w += sig * h[3];
            o1.x += sig * h[4]; o1.y += sig * h[5]; o1.z += sig * h[6]; o1.w += sig * h[7];
            out[node * 16 + 2 * l]     = o0;
            out[node * 16 + 2 * l + 1] = o1;
        }
    }
}

// ---- deferred pooling epilogue ------------------------------------------
// out = sum_t sigmoid((g_t . s)/nv) * g_t / nv   over t=0..KHOPS
// (g_t = h_t * nv, with h_0 = features). One streaming pass, out written once.

__global__ void pool_epilogue(const uint4* __restrict__ gbase, size_t gstride,
                              const float* __restrict__ norm,
                              const float* __restrict__ s,
                              float4* __restrict__ out, int N) {
    int t0 = blockIdx.x * blockDim.x + threadIdx.x;
    int node = t0 >> 3;
    int l = t0 & 7;
    if (node >= N) return;          // uniform per 8-lane group
    float inv_nv = 1.0f / norm[node];
    const float4* s4 = (const float4*)s;
    float4 sa = s4[2 * l], sb = s4[2 * l + 1];
    float o[8] = {0.f, 0.f, 0.f, 0.f, 0.f, 0.f, 0.f, 0.f};
    for (int t = 0; t <= KHOPS; ++t) {
        U4H P; P.u = gbase[(size_t)t * gstride + (size_t)node * 8 + l];
        float2 a0 = __half22float2(P.h[0]), a1 = __half22float2(P.h[1]);
        float2 a2 = __half22float2(P.h[2]), a3 = __half22float2(P.h[3]);
        float gf[8] = {a0.x, a0.y, a1.x, a1.y, a2.x, a2.y, a3.x, a3.y};
        float dot = gf[0] * sa.x + gf[1] * sa.y + gf[2] * sa.z + gf[3] * sa.w
                  + gf[4] * sb.x + gf[5] * sb.y + gf[6] * sb.z + gf[7] * sb.w;
        #pragma unroll
        for (int m = 1; m <= 4; m <<= 1) dot += __shfl_xor(dot, m, 64);
        float sig = 1.0f / (1.0f + expf(-dot * inv_nv));
        float sc = sig * inv_nv;
        #pragma unroll
        for (int j = 0; j < 8; ++j) o[j] += sc * gf[j];
    }
    out[node * 16 + 2 * l]     = make_float4(o[0], o[1], o[2], o[3]);
    out[node * 16 + 2 * l + 1] = make_float4(o[4], o[5], o[6], o[7]);
}

// ---- launcher -----------------------------------------------------------

extern "C" void kernel_launch(void* const* d_in, const int* in_sizes, int n_in,
                              void* d_out, int out_size, void* d_ws, size_t ws_size,
                              hipStream_t stream) {
    const float* feat = (const float*)d_in[0];
    const float* s    = (const float*)d_in[1];
    const int*   src  = (const int*)d_in[2];
    const int*   dst  = (const int*)d_in[3];

    int N = in_sizes[0] / D;
    int E = in_sizes[2];
    int NR   = (N + RB - 1) / RB;          // 98 ranges  (<= NRMAX)
    int NBLK = (E + EB - 1) / EB;          // 782 edge blocks
    int M    = NR * NBLK;
    int nchA = (M + 1023) / 1024;

    // fixed workspace layout
    int*   offsets  = (int*)d_ws;                  // N+1
    int*   csr      = offsets + (N + 1);           // E
    float* norm     = (float*)(csr + E);           // N
    int*   countsA  = (int*)(norm + N);            // M
    int*   baseA    = countsA + M;                 // M
    int*   bsumA    = baseA + M;                   // nchA
    uintptr_t p = (uintptr_t)(bsumA + nchA);
    p = (p + 255) & ~(uintptr_t)255;
    uint4* gbase = (uint4*)p;                      // f16 rows: (N+1)*8 uint4/buffer
    size_t gstride = (size_t)(N + 1) * 8;          // uint4 per buffer (row N = zeros)

    // deferred pooling needs KHOPS+1 g buffers; fall back to 2-buffer ping-pong
    size_t fixed_bytes = (uintptr_t)gbase - (uintptr_t)d_ws;
    int deferred = (ws_size >= fixed_bytes + (size_t)(KHOPS + 1) * gstride * sizeof(uint4)) ? 1 : 0;

    // ebuf2 (E u32 = 6.4MB) aliases g buffer #1 (first written by the first
    // spmm hop, after range_build has consumed ebuf2)
    unsigned int* ebuf2 = (unsigned int*)(gbase + gstride);

    // multisplit CSR build (zero global atomics)
    countA<<<NBLK, 256, 0, stream>>>(dst, countsA, E, NR, NBLK);
    block_sums<<<nchA, 256, 0, stream>>>(countsA, bsumA, M);
    scan_bsums<<<1, 1024, 0, stream>>>(bsumA, nchA);
    gen_scan2<<<nchA, 1024, 0, stream>>>(countsA, bsumA, baseA, M);
    passA2<<<NBLK, 256, 0, stream>>>(src, dst, baseA, ebuf2, E, NR, NBLK);
    range_build<<<NR, RB, 0, stream>>>(ebuf2, baseA, offsets, norm, csr, N, E, NR, NBLK);

    float4* outp = (float4*)d_out;
    int nb_node8 = ((N + 1) * 8 + 255) / 256;      // MUST cover pad node N
    int nb_spmm  = (N + 4) / 4;                    // +1 node for pad row

    hop0<<<nb_node8, 256, 0, stream>>>((const float4*)feat, s, norm, gbase,
                                       outp, N, deferred ? 0 : 1);

    if (deferred) {
        for (int t = 0; t < KHOPS; ++t) {
            spmm_hop<<<nb_spmm, 256, 0, stream>>>(
                gbase + (size_t)t * gstride, offsets, csr, norm, s,
                gbase + (size_t)(t + 1) * gstride, outp, N, 0, 1);
        }
        pool_epilogue<<<nb_node8, 256, 0, stream>>>(gbase, gstride, norm, s, outp, N);
    } else {
        uint4* gin = gbase;
        uint4* gout = gbase + gstride;
        for (int t = 0; t < KHOPS; ++t) {
            spmm_hop<<<nb_spmm, 256, 0, stream>>>(
                gin, offsets, csr, norm, s, gout, outp, N, 1, (t < KHOPS - 1) ? 1 : 0);
            uint4* tmp = gin; gin = gout; gout = tmp;
        }
    }
}